// Round 4
// baseline (1376.411 us; speedup 1.0000x reference)
//
#include <hip/hip_runtime.h>
#include <hip/hip_bf16.h>
#include <math.h>

#define N_NODES 100000
#define N_EDGES 1600000
#define N_GRAPHS 1024
#define NB_SCAN ((N_NODES + 255) / 256)   // 391

// ---------------- layer 1: node linear (128 -> 64) x4 matrices ----------------
__global__ __launch_bounds__(256) void node_lin1(const float* __restrict__ x,
                          const float* __restrict__ Wq, const float* __restrict__ bq,
                          const float* __restrict__ Wk, const float* __restrict__ bk,
                          const float* __restrict__ Wv, const float* __restrict__ bv,
                          const float* __restrict__ Ws, const float* __restrict__ bs,
                          float* __restrict__ q, float* __restrict__ k,
                          float* __restrict__ v, float* __restrict__ s) {
    __shared__ float xs[16][128];
    int tid = threadIdx.x;
    int nb = blockIdx.x * 16;
    for (int i = tid; i < 16 * 128; i += 256) xs[i >> 7][i & 127] = x[(size_t)nb * 128 + i];
    __syncthreads();
    int w = tid >> 6, t = tid & 63;
    const float* W = (w == 0) ? Wq : (w == 1) ? Wk : (w == 2) ? Wv : Ws;
    const float* b = (w == 0) ? bq : (w == 1) ? bk : (w == 2) ? bv : bs;
    float* out = (w == 0) ? q : (w == 1) ? k : (w == 2) ? v : s;
    float acc[16];
#pragma unroll
    for (int n = 0; n < 16; ++n) acc[n] = 0.f;
#pragma unroll 4
    for (int j = 0; j < 128; ++j) {
        float wv = W[j * 64 + t];
#pragma unroll
        for (int n = 0; n < 16; ++n) acc[n] += xs[n][j] * wv;
    }
    float bb = b[t];
#pragma unroll
    for (int n = 0; n < 16; ++n) {
        int nn = nb + n;
        if (nn < N_NODES) out[(size_t)nn * 64 + t] = acc[n] + bb;
    }
}

// ---------------- layer 2: node linear (64 -> 16) x4 ----------------
__global__ __launch_bounds__(256) void node_lin2(const float* __restrict__ h,
                          const float* __restrict__ Wq, const float* __restrict__ bq,
                          const float* __restrict__ Wk, const float* __restrict__ bk,
                          const float* __restrict__ Wv, const float* __restrict__ bv,
                          const float* __restrict__ Ws, const float* __restrict__ bs,
                          float* __restrict__ q, float* __restrict__ k,
                          float* __restrict__ v, float* __restrict__ s) {
    __shared__ float hs[32][65];
    int tid = threadIdx.x;
    int nb = blockIdx.x * 32;
    for (int i = tid; i < 32 * 64; i += 256) {
        int nn = nb + (i >> 6);
        hs[i >> 6][i & 63] = (nn < N_NODES) ? h[(size_t)nb * 64 + i] : 0.f;
    }
    __syncthreads();
    int w = tid >> 6, t = tid & 63, g = t >> 4, c = t & 15;
    const float* W = (w == 0) ? Wq : (w == 1) ? Wk : (w == 2) ? Wv : Ws;
    const float* b = (w == 0) ? bq : (w == 1) ? bk : (w == 2) ? bv : bs;
    float* out = (w == 0) ? q : (w == 1) ? k : (w == 2) ? v : s;
    float acc[8];
#pragma unroll
    for (int n = 0; n < 8; ++n) acc[n] = 0.f;
#pragma unroll 4
    for (int j = 0; j < 64; ++j) {
        float wv = W[j * 16 + c];
#pragma unroll
        for (int n = 0; n < 8; ++n) acc[n] += hs[g * 8 + n][j] * wv;
    }
    float bb = b[c];
#pragma unroll
    for (int n = 0; n < 8; ++n) {
        int nn = nb + g * 8 + n;
        if (nn < N_NODES) out[(size_t)nn * 16 + c] = acc[n] + bb;
    }
}

// ---------------- CSR build: histogram -> scan -> scatter ----------------
__global__ void hist_kernel(const int* __restrict__ ei, int* __restrict__ deg) {
    int e = blockIdx.x * blockDim.x + threadIdx.x;
    if (e < N_EDGES) atomicAdd(deg + ei[N_EDGES + e], 1);
}

__global__ __launch_bounds__(256) void scan_block(const int* __restrict__ deg,
        int* __restrict__ rowptr, int* __restrict__ bsum) {
    __shared__ int sd[256];
    int i = blockIdx.x * 256 + threadIdx.x;
    int v = (i < N_NODES) ? deg[i] : 0;
    sd[threadIdx.x] = v;
    __syncthreads();
    for (int off = 1; off < 256; off <<= 1) {
        int add = (threadIdx.x >= off) ? sd[threadIdx.x - off] : 0;
        __syncthreads();
        sd[threadIdx.x] += add;
        __syncthreads();
    }
    if (i < N_NODES) rowptr[i] = sd[threadIdx.x] - v;   // exclusive within block
    if (threadIdx.x == 255) bsum[blockIdx.x] = sd[255];
}

__global__ __launch_bounds__(512) void scan_bsum(int* __restrict__ bsum) {
    __shared__ int sd[512];
    int t = threadIdx.x;
    int v = (t < NB_SCAN) ? bsum[t] : 0;
    sd[t] = v;
    __syncthreads();
    for (int off = 1; off < 512; off <<= 1) {
        int add = (t >= off) ? sd[t - off] : 0;
        __syncthreads();
        sd[t] += add;
        __syncthreads();
    }
    if (t < NB_SCAN) bsum[t] = sd[t] - v;               // exclusive
}

__global__ void scan_add(int* __restrict__ rowptr, int* __restrict__ cursor,
                         const int* __restrict__ bsum) {
    int i = blockIdx.x * blockDim.x + threadIdx.x;
    if (i < N_NODES) {
        int r = rowptr[i] + bsum[i >> 8];
        rowptr[i] = r;
        cursor[i] = r;
    }
    if (i == 0) rowptr[N_NODES] = N_EDGES;
}

__global__ void scatter_kernel(const int* __restrict__ ei, int* __restrict__ cursor,
                               int2* __restrict__ sorted) {
    int e = blockIdx.x * blockDim.x + threadIdx.x;
    if (e >= N_EDGES) return;
    int d = ei[N_EDGES + e];
    int pos = atomicAdd(cursor + d, 1);
    sorted[pos] = make_int2(ei[e], e);   // (src, eid)
}

// ---------------- layer 1: per-dst fused attention (atomic-free) ----------------
// one wave per dst node; 64 lanes = 64 channels
__global__ __launch_bounds__(256) void agg_l1(const int2* __restrict__ sorted,
        const int* __restrict__ rowptr, const float* __restrict__ ea,
        const float* __restrict__ q, const float* __restrict__ k,
        const float* __restrict__ v, const float* __restrict__ We,
        float* __restrict__ h /* in: skip, out: relu result */) {
    int w = threadIdx.x >> 6, t = threadIdx.x & 63;
    int n = blockIdx.x * 4 + w;
    if (n >= N_NODES) return;
    float we[32];
#pragma unroll
    for (int j = 0; j < 32; ++j) we[j] = We[j * 64 + t];
    float qv = q[(size_t)n * 64 + t];
    int beg = rowptr[n], end = rowptr[n + 1];
    float den = 0.f, acc = 0.f;
    for (int idx = beg; idx < end; ++idx) {
        int2 se = sorted[idx];
        const float4* eap = (const float4*)(ea + (size_t)se.y * 32);
        float4 ef[8];
#pragma unroll
        for (int r = 0; r < 8; ++r) ef[r] = eap[r];
        float kv = k[(size_t)se.x * 64 + t];
        float vv = v[(size_t)se.x * 64 + t];
        float et = 0.f;
#pragma unroll
        for (int r = 0; r < 8; ++r)
            et += ef[r].x * we[4 * r] + ef[r].y * we[4 * r + 1] +
                  ef[r].z * we[4 * r + 2] + ef[r].w * we[4 * r + 3];
        float p = qv * (kv + et);
#pragma unroll
        for (int m = 32; m > 0; m >>= 1) p += __shfl_xor(p, m, 64);
        float a = __expf(p * 0.125f);
        den += a;
        acc += a * (vv + et);
    }
    size_t o = (size_t)n * 64 + t;
    float r2 = acc / (den + 1e-16f) + h[o];
    h[o] = r2 > 0.f ? r2 : 0.f;
}

// ---------------- layer 2: per-dst fused attention + mean-pool ----------------
// one wave per dst; 4 groups x 16 lanes: group g processes edges idx = beg+g, +4...
__global__ __launch_bounds__(256) void agg_l2(const int2* __restrict__ sorted,
        const int* __restrict__ rowptr, const float* __restrict__ ea,
        const float* __restrict__ q, const float* __restrict__ k,
        const float* __restrict__ v, const float* __restrict__ We,
        const float* __restrict__ skip, const int* __restrict__ batch,
        float* __restrict__ sums, float* __restrict__ cnt) {
    int w = threadIdx.x >> 6, t = threadIdx.x & 63;
    int n = blockIdx.x * 4 + w;
    if (n >= N_NODES) return;
    int g = t >> 4, c = t & 15;
    float we[32];
#pragma unroll
    for (int j = 0; j < 32; ++j) we[j] = We[j * 16 + c];
    float qv = q[(size_t)n * 16 + c];
    int beg = rowptr[n], end = rowptr[n + 1];
    float den = 0.f, acc = 0.f;
    for (int idx = beg + g; idx < end; idx += 4) {
        int2 se = sorted[idx];
        const float4* eap = (const float4*)(ea + (size_t)se.y * 32);
        float4 ef[8];
#pragma unroll
        for (int r = 0; r < 8; ++r) ef[r] = eap[r];
        float kv = k[(size_t)se.x * 16 + c];
        float vv = v[(size_t)se.x * 16 + c];
        float et = 0.f;
#pragma unroll
        for (int r = 0; r < 8; ++r)
            et += ef[r].x * we[4 * r] + ef[r].y * we[4 * r + 1] +
                  ef[r].z * we[4 * r + 2] + ef[r].w * we[4 * r + 3];
        float p = qv * (kv + et);
        p += __shfl_xor(p, 8, 64);
        p += __shfl_xor(p, 4, 64);
        p += __shfl_xor(p, 2, 64);
        p += __shfl_xor(p, 1, 64);
        float a = __expf(p * 0.25f);
        den += a;
        acc += a * (vv + et);
    }
    den += __shfl_xor(den, 16, 64);
    den += __shfl_xor(den, 32, 64);
    acc += __shfl_xor(acc, 16, 64);
    acc += __shfl_xor(acc, 32, 64);
    if (t < 16) {
        float r2 = acc / (den + 1e-16f) + skip[(size_t)n * 16 + c];
        r2 = r2 > 0.f ? r2 : 0.f;
        int gb = batch[n];
        atomicAdd(sums + gb * 16 + c, r2);
        if (c == 0) atomicAdd(cnt + gb, 1.0f);
    }
}

// ---------------- final fc + sigmoid ----------------
__global__ void final_fc(const float* __restrict__ sums, const float* __restrict__ cnt,
                         const float* __restrict__ Wf, const float* __restrict__ bf,
                         float* __restrict__ out) {
    int g = blockIdx.x * blockDim.x + threadIdx.x;
    if (g >= N_GRAPHS) return;
    float cc = cnt[g];
    cc = cc > 1.f ? cc : 1.f;
    float acc = bf[0];
#pragma unroll
    for (int c = 0; c < 16; ++c) acc += (sums[g * 16 + c] / cc) * Wf[c];
    out[g] = 1.f / (1.f + expf(-acc));
}

extern "C" void kernel_launch(void* const* d_in, const int* in_sizes, int n_in,
                              void* d_out, int out_size, void* d_ws, size_t ws_size,
                              hipStream_t stream) {
    const float* x    = (const float*)d_in[0];
    const float* ea   = (const float*)d_in[1];
    const float* Wq1  = (const float*)d_in[2];
    const float* bq1  = (const float*)d_in[3];
    const float* Wk1  = (const float*)d_in[4];
    const float* bk1  = (const float*)d_in[5];
    const float* Wv1  = (const float*)d_in[6];
    const float* bv1  = (const float*)d_in[7];
    const float* We1  = (const float*)d_in[8];
    const float* Ws1  = (const float*)d_in[9];
    const float* bs1  = (const float*)d_in[10];
    const float* Wq2  = (const float*)d_in[11];
    const float* bq2  = (const float*)d_in[12];
    const float* Wk2  = (const float*)d_in[13];
    const float* bk2  = (const float*)d_in[14];
    const float* Wv2  = (const float*)d_in[15];
    const float* bv2  = (const float*)d_in[16];
    const float* We2  = (const float*)d_in[17];
    const float* Ws2  = (const float*)d_in[18];
    const float* bs2  = (const float*)d_in[19];
    const float* Wf   = (const float*)d_in[20];
    const float* bf   = (const float*)d_in[21];
    const int*   ei   = (const int*)d_in[22];
    const int*   batch= (const int*)d_in[23];
    float* out = (float*)d_out;

    // -------- workspace layout --------
    float* ws = (float*)d_ws;
    size_t off = 0;
    float* q1 = ws + off; off += (size_t)N_NODES * 64;
    float* k1 = ws + off; off += (size_t)N_NODES * 64;
    float* v1 = ws + off; off += (size_t)N_NODES * 64;
    float* s1 = ws + off; off += (size_t)N_NODES * 64;   // skip -> h1
    float* q2 = ws + off; off += (size_t)N_NODES * 16;
    float* k2 = ws + off; off += (size_t)N_NODES * 16;
    float* v2 = ws + off; off += (size_t)N_NODES * 16;
    float* s2 = ws + off; off += (size_t)N_NODES * 16;   // skip for layer 2
    int2* sorted = (int2*)(ws + off); off += (size_t)N_EDGES * 2;
    int* rowptr  = (int*)(ws + off);  off += N_NODES + 2;
    int* cursor  = (int*)(ws + off);  off += N_NODES;
    int* bsum    = (int*)(ws + off);  off += 512;
    // ---- contiguous zero block ----
    float* zerop = ws + off;
    int*   deg   = (int*)(ws + off);  off += N_NODES;
    float* sums  = ws + off;          off += (size_t)N_GRAPHS * 16;
    float* cnt   = ws + off;          off += N_GRAPHS;
    size_t zero_bytes = ((size_t)N_NODES + N_GRAPHS * 16 + N_GRAPHS) * sizeof(float);
    hipMemsetAsync(zerop, 0, zero_bytes, stream);

    // -------- CSR build (shared by both layers) --------
    hist_kernel<<<(N_EDGES + 255) / 256, 256, 0, stream>>>(ei, deg);
    scan_block<<<NB_SCAN, 256, 0, stream>>>(deg, rowptr, bsum);
    scan_bsum<<<1, 512, 0, stream>>>(bsum);
    scan_add<<<NB_SCAN, 256, 0, stream>>>(rowptr, cursor, bsum);
    scatter_kernel<<<(N_EDGES + 255) / 256, 256, 0, stream>>>(ei, cursor, sorted);

    // -------- layer 1 --------
    node_lin1<<<(N_NODES + 15) / 16, 256, 0, stream>>>(x, Wq1, bq1, Wk1, bk1, Wv1, bv1,
                                                       Ws1, bs1, q1, k1, v1, s1);
    agg_l1<<<(N_NODES + 3) / 4, 256, 0, stream>>>(sorted, rowptr, ea, q1, k1, v1, We1, s1);

    // -------- layer 2 --------
    node_lin2<<<(N_NODES + 31) / 32, 256, 0, stream>>>(s1, Wq2, bq2, Wk2, bk2, Wv2, bv2,
                                                       Ws2, bs2, q2, k2, v2, s2);
    agg_l2<<<(N_NODES + 3) / 4, 256, 0, stream>>>(sorted, rowptr, ea, q2, k2, v2, We2,
                                                  s2, batch, sums, cnt);

    // -------- final fc --------
    final_fc<<<(N_GRAPHS + 255) / 256, 256, 0, stream>>>(sums, cnt, Wf, bf, out);
}